// Round 8
// baseline (107.162 us; speedup 1.0000x reference)
//
#include <hip/hip_runtime.h>

#define Hn 128
#define Ln 2048
#define NBn 64
#define K 64          // chunk length
#define G 32          // chunks: G*K == Ln
#define PITCH 65      // 64+1: bank (n+k)%32 per phase -> conflict-free b32
                      // (measured 0 conflicts R1/R7; PITCH 68+b128 was 8-way)

// w-space: w = 2*C*z follows the same diagonal recurrence with input
// coefficient 2*C*B;  y_t = sum_n Re(w_n) + D*u_t;  final z = w/(2C).
// ws layout: Sum[(h*G+g)*NBn+n] float4 {a_re,a_im,b_re,b_im} (4 MB)

// ---------------------------------------------------------------------------
// Phase 1: per-(h,chunk) local w-space scan (s_in = 0).
//   y_local (incl. D*u) -> out;  chunk summary float4 -> Sum.
//   Reset folded into per-step Lam coeff (off the 2-fma dependent chain).
// ---------------------------------------------------------------------------
__global__ __launch_bounds__(64) void phase1_local(
    const float* __restrict__ u,
    const float* __restrict__ Lre,  const float* __restrict__ Lim,
    const float* __restrict__ Bre,  const float* __restrict__ Bim,
    const float* __restrict__ Cre,  const float* __restrict__ Cim,
    const float* __restrict__ Dv,   const int* __restrict__ dflag,
    float* __restrict__ out,
    float4* __restrict__ Sum)
{
    __shared__ float g_s[K * PITCH];
    __shared__ float u_s[K];

    const int g = blockIdx.x, h = blockIdx.y, n = threadIdx.x;
    const int hn = h * NBn + n;
    const int l0 = g * K;

    const float lre = Lre[hn], lim = Lim[hn];
    const float br  = Bre[hn], bi  = Bim[hn];
    const float cr  = Cre[hn], ci  = Cim[hn];
    const float Dh  = Dv[h];
    const float cbr2 = 2.f * (cr * br - ci * bi);   // 2*C*B
    const float cbi2 = 2.f * (cr * bi + ci * br);

    u_s[n] = u[h * Ln + l0 + n];
    const unsigned long long m = __ballot(dflag[l0 + n] != 0);
    __syncthreads();

    float wr = 0.f, wi = 0.f;
    if (m == 0ull) {                 // reset-free chunk (~53%)
        #pragma unroll
        for (int k = 0; k < K; ++k) {
            const float uk = u_s[k];               // LDS broadcast (DS pipe)
            const float nr = fmaf(lre, wr, fmaf(-lim, wi, cbr2 * uk));
            const float ni = fmaf(lre, wi, fmaf( lim, wr, cbi2 * uk));
            wr = nr; wi = ni;
            g_s[k * PITCH + n] = wr;               // only Re needed for y
        }
    } else {
        #pragma unroll
        for (int k = 0; k < K; ++k) {
            const bool  rs  = (m >> k) & 1ull;     // wave-uniform select
            const float lrk = rs ? 0.f : lre;
            const float lik = rs ? 0.f : lim;
            const float uk  = u_s[k];
            const float nr = fmaf(lrk, wr, fmaf(-lik, wi, cbr2 * uk));
            const float ni = fmaf(lrk, wi, fmaf( lik, wr, cbi2 * uk));
            wr = nr; wi = ni;
            g_s[k * PITCH + n] = wr;
        }
    }
    __syncthreads();

    // lane t sums row t (timestep l0+t): conflict-free b32 at PITCH 65
    const float* row = g_s + n * PITCH;
    float a0 = 0.f, a1 = 0.f, a2 = 0.f, a3 = 0.f;
    #pragma unroll
    for (int k = 0; k < NBn; k += 4) {
        a0 += row[k + 0]; a1 += row[k + 1];
        a2 += row[k + 2]; a3 += row[k + 3];
    }
    out[h * Ln + l0 + n] = (a0 + a1) + (a2 + a3) + Dh * u_s[n];

    // chunk summary: Lam^64 via 6 squarings, zeroed if any reset in chunk
    float pr = lre, pi = lim;
    #pragma unroll
    for (int it = 0; it < 6; ++it) {
        const float sr2 = pr * pr - pi * pi;
        const float si2 = 2.f * pr * pi;
        pr = sr2; pi = si2;
    }
    if (m) { pr = 0.f; pi = 0.f; }
    Sum[(h * G + g) * NBn + n] = make_float4(pr, pi, wr, wi);
}

// ---------------------------------------------------------------------------
// Phase 2+3 fused: block (g,h) computes its own incoming w-state via a
// FULLY-UNROLLED predicated prefix over all 32 chunk summaries (32
// independent dwordx4 loads issue up front; only the 32x8cyc FMA chain is
// serial — this avoids R3's non-unrolled latency-chain pathology), then the
// correction  y[l0+k] += sum_n Re(Lam_n^{k+1} w_in_n)  masked from the first
// reset onward. Block g==G-1 also emits the final state z = w/(2C).
// ---------------------------------------------------------------------------
__global__ __launch_bounds__(64) void phase23_fixup(
    const float* __restrict__ x_re, const float* __restrict__ x_im,
    const float* __restrict__ Lre,  const float* __restrict__ Lim,
    const float* __restrict__ Cre,  const float* __restrict__ Cim,
    const int* __restrict__ dflag,
    const float4* __restrict__ Sum,
    float* __restrict__ out)
{
    __shared__ float g_s[K * PITCH];

    const int g = blockIdx.x, h = blockIdx.y, n = threadIdx.x;
    const int hn = h * NBn + n;
    const int l0 = g * K;

    const float cr = Cre[hn], ci = Cim[hn];
    const float x0r = x_re[hn], x0i = x_im[hn];
    float sre = 2.f * (cr * x0r - ci * x0i);    // w-space initial state
    float sim = 2.f * (cr * x0i + ci * x0r);

    const float4* base = Sum + h * G * NBn + n;
    #pragma unroll
    for (int j = 0; j < G; ++j) {               // fixed trip: full unroll,
        const float4 s = base[j * NBn];         // loads hoisted & pipelined
        if (j < g) {                            // block-uniform predicate
            const float nr = fmaf(s.x, sre, fmaf(-s.y, sim, s.z));
            const float ni = fmaf(s.x, sim, fmaf( s.y, sre, s.w));
            sre = nr; sim = ni;
        }
    }
    // (sre,sim) = w_in for this chunk (same fmaf sequence as old phase2)

    if (g == G - 1) {                           // final state
        const float4 s = base[(G - 1) * NBn];
        const float fr = fmaf(s.x, sre, fmaf(-s.y, sim, s.z));
        const float fi = fmaf(s.x, sim, fmaf( s.y, sre, s.w));
        const float c2r = 2.f * cr, c2i = 2.f * ci;
        const float inv = 1.f / (c2r * c2r + c2i * c2i);
        float* xlast = out + Hn * Ln;
        xlast[2 * hn + 0] = (fr * c2r + fi * c2i) * inv;
        xlast[2 * hn + 1] = (fi * c2r - fr * c2i) * inv;
    }

    // ---- correction: two interleaved Lam^2 chains (half dependent depth) --
    const float lre = Lre[hn], lim = Lim[hn];
    const unsigned long long bal = __ballot(dflag[l0 + n] != 0);
    const int kr = bal ? (__ffsll((long long)bal) - 1) : K;

    const float l2r = lre * lre - lim * lim;    // Lam^2
    const float l2i = 2.f * lre * lim;

    float tAr = fmaf(lre, sre, -lim * sim);     // k=0: w_in*Lam
    float tAi = fmaf(lre, sim,  lim * sre);
    float tBr = fmaf(l2r, sre, -l2i * sim);     // k=1: w_in*Lam^2
    float tBi = fmaf(l2r, sim,  l2i * sre);
    g_s[0 * PITCH + n] = tAr;
    g_s[1 * PITCH + n] = tBr;
    #pragma unroll
    for (int k = 2; k < K; k += 2) {
        const float nAr = fmaf(l2r, tAr, -l2i * tAi);
        const float nAi = fmaf(l2r, tAi,  l2i * tAr);
        tAr = nAr; tAi = nAi;
        g_s[k * PITCH + n] = tAr;
        const float nBr = fmaf(l2r, tBr, -l2i * tBi);
        const float nBi = fmaf(l2r, tBi,  l2i * tBr);
        tBr = nBr; tBi = nBi;
        g_s[(k + 1) * PITCH + n] = tBr;
    }
    __syncthreads();

    const float* row = g_s + n * PITCH;
    float a0 = 0.f, a1 = 0.f, a2 = 0.f, a3 = 0.f;
    #pragma unroll
    for (int k = 0; k < NBn; k += 4) {
        a0 += row[k + 0]; a1 += row[k + 1];
        a2 += row[k + 2]; a3 += row[k + 3];
    }
    if (n < kr)
        out[h * Ln + l0 + n] += (a0 + a1) + (a2 + a3);
}

extern "C" void kernel_launch(void* const* d_in, const int* in_sizes, int n_in,
                              void* d_out, int out_size, void* d_ws, size_t ws_size,
                              hipStream_t stream) {
    const float* u    = (const float*)d_in[0];
    const float* x_re = (const float*)d_in[1];
    const float* x_im = (const float*)d_in[2];
    const float* Lre  = (const float*)d_in[3];
    const float* Lim  = (const float*)d_in[4];
    const float* Bre  = (const float*)d_in[5];
    const float* Bim  = (const float*)d_in[6];
    const float* Cre  = (const float*)d_in[7];
    const float* Cim  = (const float*)d_in[8];
    const float* Dv   = (const float*)d_in[9];
    const int*   dfl  = (const int*)d_in[10];
    float* out = (float*)d_out;

    float4* Sum = (float4*)d_ws;           // 4 MB

    dim3 grid(G, Hn);
    phase1_local<<<grid, 64, 0, stream>>>(u, Lre, Lim, Bre, Bim, Cre, Cim,
                                          Dv, dfl, out, Sum);
    phase23_fixup<<<grid, 64, 0, stream>>>(x_re, x_im, Lre, Lim, Cre, Cim,
                                           dfl, Sum, out);
}